// Round 1
// baseline (2391.454 us; speedup 1.0000x reference)
//
#include <hip/hip_runtime.h>

#define N_NODES 100000
#define N_EDGES 600000
#define D 128

// ws layout (floats): S[N*D] | Ea[N*D] | deg[N] | Wcat[512*128] | bv[128]
// out[n] = [h[n] | S[n] | deg[n]*h[n] | Ea[n]] @ Wcat + deg[n]*bv + b_upd
// Wcat rows: 0..127   = W_upd[0:128]            (h     -> Wu1)
//            128..255 = W_msg[0:128]@Wu2        (S     -> W1@Wu2)
//            256..383 = W_msg[128:256]@Wu2      (deg*h -> W2@Wu2)
//            384..511 = W_msg[256:384]@Wu2      (Ea    -> W3@Wu2)
// bv = b_msg @ Wu2

__global__ void k_build_w(const float* __restrict__ W_msg,
                          const float* __restrict__ b_msg,
                          const float* __restrict__ W_upd,
                          float* __restrict__ Wcat,
                          float* __restrict__ bv)
{
    int gid = blockIdx.x * 256 + threadIdx.x;
    if (gid < 512 * 128) {
        int k = gid >> 7, j = gid & 127;
        if (k < 128) {
            Wcat[gid] = W_upd[k * 128 + j];
        } else {
            int r = k - 128;  // row of W_msg, 0..383 (ordering matches X layout)
            float acc = 0.f;
            #pragma unroll 4
            for (int dd = 0; dd < 128; ++dd)
                acc += W_msg[r * 128 + dd] * W_upd[(128 + dd) * 128 + j];
            Wcat[gid] = acc;
        }
    } else if (gid < 512 * 128 + 128) {
        int j = gid - 512 * 128;
        float acc = 0.f;
        for (int dd = 0; dd < 128; ++dd)
            acc += b_msg[dd] * W_upd[(128 + dd) * 128 + j];
        bv[j] = acc;
    }
}

// 32 threads per edge, 4 floats per thread (float4). 8 edges / 256-thread block.
__global__ void k_edge_scatter(const float* __restrict__ h,
                               const int* __restrict__ eidx,
                               const float* __restrict__ ea,
                               float* __restrict__ S,
                               float* __restrict__ Ea,
                               float* __restrict__ deg)
{
    int tid = blockIdx.x * 256 + threadIdx.x;
    int e = tid >> 5;
    int dg = tid & 31;
    int d = dg * 4;
    int s = eidx[e];
    int r = eidx[N_EDGES + e];
    const float4 hv = *reinterpret_cast<const float4*>(h + (size_t)s * D + d);
    const float4 ev = *reinterpret_cast<const float4*>(ea + (size_t)e * D + d);
    float* Sp = S + (size_t)r * D + d;
    float* Ep = Ea + (size_t)r * D + d;
    atomicAdd(Sp + 0, hv.x); atomicAdd(Sp + 1, hv.y);
    atomicAdd(Sp + 2, hv.z); atomicAdd(Sp + 3, hv.w);
    atomicAdd(Ep + 0, ev.x); atomicAdd(Ep + 1, ev.y);
    atomicAdd(Ep + 2, ev.z); atomicAdd(Ep + 3, ev.w);
    if (dg == 0) atomicAdd(deg + r, 1.0f);
}

// [N,512] @ [512,128] fp32. Block = 256 threads, 32 nodes. Each thread: 4 rows x 4 cols.
__global__ __launch_bounds__(256, 2) void k_node_gemm(
    const float* __restrict__ h,
    const float* __restrict__ S,
    const float* __restrict__ Ea,
    const float* __restrict__ deg,
    const float* __restrict__ Wcat,
    const float* __restrict__ bv,
    const float* __restrict__ b_upd,
    float* __restrict__ out)
{
    __shared__ float X[32][512];   // 64 KB
    __shared__ float Wt[32][128];  // 16 KB
    const int tid = threadIdx.x;
    const int n0 = blockIdx.x * 32;

    // Stage X = [h | S | deg*h | Ea] for 32 nodes. 16 float4 per thread, coalesced.
    for (int q = tid; q < 32 * 128; q += 256) {
        int i = q >> 7, c = q & 127;  // c = float4 column 0..127
        int n = n0 + i;
        float4 v;
        if (c < 32)      v = *(const float4*)(h  + (size_t)n * D + c * 4);
        else if (c < 64) v = *(const float4*)(S  + (size_t)n * D + (c - 32) * 4);
        else if (c < 96) {
            v = *(const float4*)(h + (size_t)n * D + (c - 64) * 4);
            float dv = deg[n];
            v.x *= dv; v.y *= dv; v.z *= dv; v.w *= dv;
        } else           v = *(const float4*)(Ea + (size_t)n * D + (c - 96) * 4);
        *(float4*)&X[i][c * 4] = v;
    }

    const int tcol = tid & 31;  // cols 4*tcol..+3
    const int trow = tid >> 5;  // rows trow + 8r
    float acc[4][4] = {};

    for (int k0 = 0; k0 < 512; k0 += 32) {
        __syncthreads();
        // stage 32x128 W tile
        for (int q = tid; q < 32 * 32; q += 256) {
            int kk = q >> 5, c = q & 31;
            *(float4*)&Wt[kk][c * 4] =
                *(const float4*)(Wcat + (size_t)(k0 + kk) * 128 + c * 4);
        }
        __syncthreads();
        #pragma unroll
        for (int kk = 0; kk < 32; ++kk) {
            float4 wv = *(const float4*)&Wt[kk][tcol * 4];
            #pragma unroll
            for (int r = 0; r < 4; ++r) {
                float xv = X[trow + 8 * r][k0 + kk];
                acc[r][0] += xv * wv.x; acc[r][1] += xv * wv.y;
                acc[r][2] += xv * wv.z; acc[r][3] += xv * wv.w;
            }
        }
    }

    float4 bvv = *(const float4*)(bv + tcol * 4);
    float4 buv = *(const float4*)(b_upd + tcol * 4);
    #pragma unroll
    for (int r = 0; r < 4; ++r) {
        int n = n0 + trow + 8 * r;
        float dv = deg[n];
        float4 o;
        o.x = acc[r][0] + dv * bvv.x + buv.x;
        o.y = acc[r][1] + dv * bvv.y + buv.y;
        o.z = acc[r][2] + dv * bvv.z + buv.z;
        o.w = acc[r][3] + dv * bvv.w + buv.w;
        *(float4*)(out + (size_t)n * D + tcol * 4) = o;
    }
}

extern "C" void kernel_launch(void* const* d_in, const int* in_sizes, int n_in,
                              void* d_out, int out_size, void* d_ws, size_t ws_size,
                              hipStream_t stream)
{
    const float* h     = (const float*)d_in[0];
    const int*   eidx  = (const int*)d_in[1];
    const float* eattr = (const float*)d_in[2];
    const float* W_msg = (const float*)d_in[3];
    const float* b_msg = (const float*)d_in[4];
    const float* W_upd = (const float*)d_in[5];
    const float* b_upd = (const float*)d_in[6];
    float* out = (float*)d_out;

    float* S    = (float*)d_ws;
    float* Ea   = S + (size_t)N_NODES * D;
    float* deg  = Ea + (size_t)N_NODES * D;
    float* Wcat = deg + N_NODES;
    float* bv   = Wcat + 512 * 128;

    hipMemsetAsync(d_ws, 0, ((size_t)2 * N_NODES * D + N_NODES) * sizeof(float), stream);
    k_build_w<<<(512 * 128 + 128 + 255) / 256, 256, 0, stream>>>(W_msg, b_msg, W_upd, Wcat, bv);
    k_edge_scatter<<<N_EDGES / 8, 256, 0, stream>>>(h, eidx, eattr, S, Ea, deg);
    k_node_gemm<<<N_NODES / 32, 256, 0, stream>>>(h, S, Ea, deg, Wcat, bv, b_upd, out);
}

// Round 2
// 492.441 us; speedup vs baseline: 4.8563x; 4.8563x over previous
//
#include <hip/hip_runtime.h>

#define N_NODES 100000
#define N_EDGES 600000
#define D 128
#define MAXDEG 64
#define OVF_CAP 4096

// ws layout (floats): S[N*D] | Ea[N*D] | deg[N] | Wcat[512*128] | bv[128]
//   then (ints):      cnt[N] | ovf_cnt[1] | ovf[OVF_CAP] | elist[N*MAXDEG]
// out[n] = [h[n] | S[n] | deg[n]*h[n] | Ea[n]] @ Wcat + deg[n]*bv + b_upd
// Wcat rows: 0..127   = W_upd[0:128]       (h     -> Wu1)
//            128..255 = W_msg[0:128]@Wu2   (S     -> W1@Wu2)
//            256..383 = W_msg[128:256]@Wu2 (deg*h -> W2@Wu2)
//            384..511 = W_msg[256:384]@Wu2 (Ea    -> W3@Wu2)
// bv = b_msg @ Wu2

__global__ void k_build_w(const float* __restrict__ W_msg,
                          const float* __restrict__ b_msg,
                          const float* __restrict__ W_upd,
                          float* __restrict__ Wcat,
                          float* __restrict__ bv)
{
    int gid = blockIdx.x * 256 + threadIdx.x;
    if (gid < 512 * 128) {
        int k = gid >> 7, j = gid & 127;
        if (k < 128) {
            Wcat[gid] = W_upd[k * 128 + j];
        } else {
            int r = k - 128;
            float acc = 0.f;
            #pragma unroll 4
            for (int dd = 0; dd < 128; ++dd)
                acc += W_msg[r * 128 + dd] * W_upd[(128 + dd) * 128 + j];
            Wcat[gid] = acc;
        }
    } else if (gid < 512 * 128 + 128) {
        int j = gid - 512 * 128;
        float acc = 0.f;
        for (int dd = 0; dd < 128; ++dd)
            acc += b_msg[dd] * W_upd[(128 + dd) * 128 + j];
        bv[j] = acc;
    }
}

// Bucket edges by receiver. 600k int atomics over 100k counters.
__global__ void k_bucket(const int* __restrict__ eidx,
                         int* __restrict__ cnt,
                         int* __restrict__ ovf_cnt,
                         int* __restrict__ ovf,
                         int* __restrict__ elist)
{
    int e = blockIdx.x * 256 + threadIdx.x;
    if (e >= N_EDGES) return;
    int r = eidx[N_EDGES + e];
    int slot = atomicAdd(cnt + r, 1);
    if (slot < MAXDEG) {
        elist[(size_t)r * MAXDEG + slot] = e;
    } else {
        int p = atomicAdd(ovf_cnt, 1);
        if (p < OVF_CAP) ovf[p] = e;
    }
}

// One wave per node: gather-sum h[send] rows and edge_attr rows. No atomics.
__global__ void k_gather(const float* __restrict__ h,
                         const int* __restrict__ eidx,
                         const float* __restrict__ ea,
                         const int* __restrict__ cnt,
                         const int* __restrict__ elist,
                         float* __restrict__ S,
                         float* __restrict__ Ea,
                         float* __restrict__ deg)
{
    int wid = (blockIdx.x * 256 + threadIdx.x) >> 6;  // wave id == node id
    int lane = threadIdx.x & 63;
    if (wid >= N_NODES) return;
    const int n = wid;
    const int c = cnt[n];
    const int m = c < MAXDEG ? c : MAXDEG;

    // each lane preloads one edge id + its send index (coalesced)
    int e_l = 0, s_l = 0;
    if (lane < m) {
        e_l = elist[(size_t)n * MAXDEG + lane];
        s_l = eidx[e_l];
    }

    float2 aS = make_float2(0.f, 0.f);
    float2 aE = make_float2(0.f, 0.f);
    for (int i = 0; i < m; ++i) {
        int e = __shfl(e_l, i);
        int s = __shfl(s_l, i);
        const float2 hv = *reinterpret_cast<const float2*>(h  + (size_t)s * D + lane * 2);
        const float2 ev = *reinterpret_cast<const float2*>(ea + (size_t)e * D + lane * 2);
        aS.x += hv.x; aS.y += hv.y;
        aE.x += ev.x; aE.y += ev.y;
    }
    *reinterpret_cast<float2*>(S  + (size_t)n * D + lane * 2) = aS;
    *reinterpret_cast<float2*>(Ea + (size_t)n * D + lane * 2) = aE;
    if (lane == 0) deg[n] = (float)c;
}

// Overflow edges (expected count 0): atomic scatter on top of gathered sums.
__global__ void k_ovf(const float* __restrict__ h,
                      const int* __restrict__ eidx,
                      const float* __restrict__ ea,
                      const int* __restrict__ ovf_cnt,
                      const int* __restrict__ ovf,
                      float* __restrict__ S,
                      float* __restrict__ Ea)
{
    int ncnt = *ovf_cnt;
    if (ncnt > OVF_CAP) ncnt = OVF_CAP;
    int lane = threadIdx.x & 63;
    int w = threadIdx.x >> 6;
    for (int i = w; i < ncnt; i += 4) {
        int e = ovf[i];
        int s = eidx[e];
        int r = eidx[N_EDGES + e];
        const float2 hv = *reinterpret_cast<const float2*>(h  + (size_t)s * D + lane * 2);
        const float2 ev = *reinterpret_cast<const float2*>(ea + (size_t)e * D + lane * 2);
        atomicAdd(S  + (size_t)r * D + lane * 2 + 0, hv.x);
        atomicAdd(S  + (size_t)r * D + lane * 2 + 1, hv.y);
        atomicAdd(Ea + (size_t)r * D + lane * 2 + 0, ev.x);
        atomicAdd(Ea + (size_t)r * D + lane * 2 + 1, ev.y);
    }
}

// [N,512] @ [512,128] fp32. Block = 256 threads, 32 nodes. Each thread: 4 rows x 4 cols.
__global__ __launch_bounds__(256, 2) void k_node_gemm(
    const float* __restrict__ h,
    const float* __restrict__ S,
    const float* __restrict__ Ea,
    const float* __restrict__ deg,
    const float* __restrict__ Wcat,
    const float* __restrict__ bv,
    const float* __restrict__ b_upd,
    float* __restrict__ out)
{
    __shared__ float X[32][512];   // 64 KB
    __shared__ float Wt[32][128];  // 16 KB
    const int tid = threadIdx.x;
    const int n0 = blockIdx.x * 32;

    for (int q = tid; q < 32 * 128; q += 256) {
        int i = q >> 7, c = q & 127;
        int n = n0 + i;
        float4 v;
        if (c < 32)      v = *(const float4*)(h  + (size_t)n * D + c * 4);
        else if (c < 64) v = *(const float4*)(S  + (size_t)n * D + (c - 32) * 4);
        else if (c < 96) {
            v = *(const float4*)(h + (size_t)n * D + (c - 64) * 4);
            float dv = deg[n];
            v.x *= dv; v.y *= dv; v.z *= dv; v.w *= dv;
        } else           v = *(const float4*)(Ea + (size_t)n * D + (c - 96) * 4);
        *(float4*)&X[i][c * 4] = v;
    }

    const int tcol = tid & 31;
    const int trow = tid >> 5;
    float acc[4][4] = {};

    for (int k0 = 0; k0 < 512; k0 += 32) {
        __syncthreads();
        for (int q = tid; q < 32 * 32; q += 256) {
            int kk = q >> 5, c = q & 31;
            *(float4*)&Wt[kk][c * 4] =
                *(const float4*)(Wcat + (size_t)(k0 + kk) * 128 + c * 4);
        }
        __syncthreads();
        #pragma unroll
        for (int kk = 0; kk < 32; ++kk) {
            float4 wv = *(const float4*)&Wt[kk][tcol * 4];
            #pragma unroll
            for (int r = 0; r < 4; ++r) {
                float xv = X[trow + 8 * r][k0 + kk];
                acc[r][0] += xv * wv.x; acc[r][1] += xv * wv.y;
                acc[r][2] += xv * wv.z; acc[r][3] += xv * wv.w;
            }
        }
    }

    float4 bvv = *(const float4*)(bv + tcol * 4);
    float4 buv = *(const float4*)(b_upd + tcol * 4);
    #pragma unroll
    for (int r = 0; r < 4; ++r) {
        int n = n0 + trow + 8 * r;
        float dv = deg[n];
        float4 o;
        o.x = acc[r][0] + dv * bvv.x + buv.x;
        o.y = acc[r][1] + dv * bvv.y + buv.y;
        o.z = acc[r][2] + dv * bvv.z + buv.z;
        o.w = acc[r][3] + dv * bvv.w + buv.w;
        *(float4*)(out + (size_t)n * D + tcol * 4) = o;
    }
}

extern "C" void kernel_launch(void* const* d_in, const int* in_sizes, int n_in,
                              void* d_out, int out_size, void* d_ws, size_t ws_size,
                              hipStream_t stream)
{
    const float* h     = (const float*)d_in[0];
    const int*   eidx  = (const int*)d_in[1];
    const float* eattr = (const float*)d_in[2];
    const float* W_msg = (const float*)d_in[3];
    const float* b_msg = (const float*)d_in[4];
    const float* W_upd = (const float*)d_in[5];
    const float* b_upd = (const float*)d_in[6];
    float* out = (float*)d_out;

    float* S    = (float*)d_ws;
    float* Ea   = S + (size_t)N_NODES * D;
    float* deg  = Ea + (size_t)N_NODES * D;
    float* Wcat = deg + N_NODES;
    float* bv   = Wcat + 512 * 128;
    int* cnt     = (int*)(bv + 128);
    int* ovf_cnt = cnt + N_NODES;
    int* ovf     = ovf_cnt + 1;
    int* elist   = ovf + OVF_CAP;

    hipMemsetAsync(cnt, 0, (N_NODES + 1) * sizeof(int), stream);
    k_build_w<<<(512 * 128 + 128 + 255) / 256, 256, 0, stream>>>(W_msg, b_msg, W_upd, Wcat, bv);
    k_bucket<<<(N_EDGES + 255) / 256, 256, 0, stream>>>(eidx, cnt, ovf_cnt, ovf, elist);
    k_gather<<<(N_NODES * 64 + 255) / 256, 256, 0, stream>>>(h, eidx, eattr, cnt, elist, S, Ea, deg);
    k_ovf<<<1, 256, 0, stream>>>(h, eidx, eattr, ovf_cnt, ovf, S, Ea);
    k_node_gemm<<<N_NODES / 32, 256, 0, stream>>>(h, S, Ea, deg, Wcat, bv, b_upd, out);
}

// Round 3
// 258.989 us; speedup vs baseline: 9.2338x; 1.9014x over previous
//
#include <hip/hip_runtime.h>

#define N_NODES 100000
#define N_EDGES 600000
#define D 128
#define MAXDEG 64
#define OVF_CAP 4096

typedef __attribute__((ext_vector_type(8))) short bf16x8;
typedef __attribute__((ext_vector_type(4))) float f32x4;

static __device__ inline ushort f2bf(float f) {
    unsigned x = __float_as_uint(f);
    unsigned r = (x + 0x7fffu + ((x >> 16) & 1u)) >> 16;  // RNE
    return (ushort)r;
}

// ws layout (floats): S[N*D] | Ea[N*D] | deg[N] | wslot[512*128] | bv[128]
//   then (ints):      cnt[N] | ovf_cnt[1] | ovf[OVF_CAP] | elist[N*MAXDEG]
// wslot holds Wfrag: 512x128 fused weight in bf16, PRE-SWIZZLED into MFMA
// B-fragment order: Wfrag[(kb*8+cb)*512 + l*8 + i] = Wcat[kb*32+(l>>4)*8+i][cb*16+(l&15)]
// Wcat rows: 0..127 = Wu1; 128..255 = W1@Wu2; 256..383 = W2@Wu2; 384..511 = W3@Wu2
// out[n] = [h[n] | S[n] | deg[n]*h[n] | Ea[n]] @ Wcat + deg[n]*bv + b_upd,  bv = b_msg@Wu2

__global__ void k_build_w(const float* __restrict__ W_msg,
                          const float* __restrict__ b_msg,
                          const float* __restrict__ W_upd,
                          ushort* __restrict__ Wfrag,
                          float* __restrict__ bv)
{
    int gid = blockIdx.x * 256 + threadIdx.x;
    if (gid < 512 * 128) {
        int i = gid & 7;
        int l = (gid >> 3) & 63;
        int fb = gid >> 9;          // kb*8 + cb
        int kb = fb >> 3, cb = fb & 7;
        int k = kb * 32 + ((l >> 4) * 8) + i;
        int j = cb * 16 + (l & 15);
        float acc;
        if (k < 128) {
            acc = W_upd[k * 128 + j];
        } else {
            int r = k - 128;
            acc = 0.f;
            #pragma unroll 4
            for (int dd = 0; dd < 128; ++dd)
                acc += W_msg[r * 128 + dd] * W_upd[(128 + dd) * 128 + j];
        }
        Wfrag[gid] = f2bf(acc);
    } else if (gid < 512 * 128 + 128) {
        int j = gid - 512 * 128;
        float acc = 0.f;
        for (int dd = 0; dd < 128; ++dd)
            acc += b_msg[dd] * W_upd[(128 + dd) * 128 + j];
        bv[j] = acc;
    }
}

// Bucket edges by receiver.
__global__ void k_bucket(const int* __restrict__ eidx,
                         int* __restrict__ cnt,
                         int* __restrict__ ovf_cnt,
                         int* __restrict__ ovf,
                         int* __restrict__ elist)
{
    int e = blockIdx.x * 256 + threadIdx.x;
    if (e >= N_EDGES) return;
    int r = eidx[N_EDGES + e];
    int slot = atomicAdd(cnt + r, 1);
    if (slot < MAXDEG) {
        elist[(size_t)r * MAXDEG + slot] = e;
    } else {
        int p = atomicAdd(ovf_cnt, 1);
        if (p < OVF_CAP) ovf[p] = e;
    }
}

// One wave per node: gather-sum h[send] rows and edge_attr rows. No atomics.
__global__ void k_gather(const float* __restrict__ h,
                         const int* __restrict__ eidx,
                         const float* __restrict__ ea,
                         const int* __restrict__ cnt,
                         const int* __restrict__ elist,
                         float* __restrict__ S,
                         float* __restrict__ Ea,
                         float* __restrict__ deg)
{
    int wid = (blockIdx.x * 256 + threadIdx.x) >> 6;
    int lane = threadIdx.x & 63;
    if (wid >= N_NODES) return;
    const int n = wid;
    const int c = cnt[n];
    const int m = c < MAXDEG ? c : MAXDEG;

    int e_l = 0, s_l = 0;
    if (lane < m) {
        e_l = elist[(size_t)n * MAXDEG + lane];
        s_l = eidx[e_l];
    }

    float2 aS = make_float2(0.f, 0.f);
    float2 aE = make_float2(0.f, 0.f);
    for (int i = 0; i < m; ++i) {
        int e = __shfl(e_l, i);
        int s = __shfl(s_l, i);
        const float2 hv = *reinterpret_cast<const float2*>(h  + (size_t)s * D + lane * 2);
        const float2 ev = *reinterpret_cast<const float2*>(ea + (size_t)e * D + lane * 2);
        aS.x += hv.x; aS.y += hv.y;
        aE.x += ev.x; aE.y += ev.y;
    }
    *reinterpret_cast<float2*>(S  + (size_t)n * D + lane * 2) = aS;
    *reinterpret_cast<float2*>(Ea + (size_t)n * D + lane * 2) = aE;
    if (lane == 0) deg[n] = (float)c;
}

// Overflow edges (expected count 0): atomic scatter on top of gathered sums.
__global__ void k_ovf(const float* __restrict__ h,
                      const int* __restrict__ eidx,
                      const float* __restrict__ ea,
                      const int* __restrict__ ovf_cnt,
                      const int* __restrict__ ovf,
                      float* __restrict__ S,
                      float* __restrict__ Ea)
{
    int ncnt = *ovf_cnt;
    if (ncnt > OVF_CAP) ncnt = OVF_CAP;
    int lane = threadIdx.x & 63;
    int w = threadIdx.x >> 6;
    for (int i = w; i < ncnt; i += 4) {
        int e = ovf[i];
        int s = eidx[e];
        int r = eidx[N_EDGES + e];
        const float2 hv = *reinterpret_cast<const float2*>(h  + (size_t)s * D + lane * 2);
        const float2 ev = *reinterpret_cast<const float2*>(ea + (size_t)e * D + lane * 2);
        atomicAdd(S  + (size_t)r * D + lane * 2 + 0, hv.x);
        atomicAdd(S  + (size_t)r * D + lane * 2 + 1, hv.y);
        atomicAdd(Ea + (size_t)r * D + lane * 2 + 0, ev.x);
        atomicAdd(Ea + (size_t)r * D + lane * 2 + 1, ev.y);
    }
}

// [N,512]@[512,128] via bf16 MFMA. Block: 256 thr = 4 waves, 32 nodes.
// Wave w: rows 16*(w>>1)..+15, cols 64*(w&1)..+63 (4 col-frags of 16).
__global__ __launch_bounds__(256, 4) void k_node_gemm(
    const float* __restrict__ h,
    const float* __restrict__ S,
    const float* __restrict__ Ea,
    const float* __restrict__ deg,
    const ushort* __restrict__ Wfrag,
    const float* __restrict__ bv,
    const float* __restrict__ b_upd,
    float* __restrict__ out)
{
    __shared__ ushort Xs[32][520];   // bf16, pad 512->520 => conflict-free b128 reads
    const int tid = threadIdx.x;
    const int n0 = blockIdx.x * 32;

    // Stage X = [h | S | deg*h | Ea] as bf16.
    for (int q = tid; q < 32 * 128; q += 256) {
        int i = q >> 7, c = q & 127;   // c = float4 column
        int n = n0 + i;
        float4 v;
        if (c < 32)      v = *(const float4*)(h  + (size_t)n * D + c * 4);
        else if (c < 64) v = *(const float4*)(S  + (size_t)n * D + (c - 32) * 4);
        else if (c < 96) {
            v = *(const float4*)(h + (size_t)n * D + (c - 64) * 4);
            float dv = deg[n];
            v.x *= dv; v.y *= dv; v.z *= dv; v.w *= dv;
        } else           v = *(const float4*)(Ea + (size_t)n * D + (c - 96) * 4);
        ushort4 u;
        u.x = f2bf(v.x); u.y = f2bf(v.y); u.z = f2bf(v.z); u.w = f2bf(v.w);
        *(ushort4*)&Xs[i][c * 4] = u;
    }
    __syncthreads();

    const int l = tid & 63;
    const int wid = tid >> 6;
    const int rb = wid >> 1;        // row block (16 rows)
    const int cbg = wid & 1;        // col group (64 cols)
    const int arow = rb * 16 + (l & 15);
    const int koff = (l >> 4) * 8;

    f32x4 acc[4] = {};
    for (int kb = 0; kb < 16; ++kb) {
        bf16x8 a = *(const bf16x8*)&Xs[arow][kb * 32 + koff];
        #pragma unroll
        for (int cc = 0; cc < 4; ++cc) {
            int fb = kb * 8 + cbg * 4 + cc;
            bf16x8 b = *(const bf16x8*)(Wfrag + ((size_t)fb * 64 + l) * 8);
            acc[cc] = __builtin_amdgcn_mfma_f32_16x16x32_bf16(a, b, acc[cc], 0, 0, 0);
        }
    }

    const int r0 = (l >> 4) * 4;
    #pragma unroll
    for (int cc = 0; cc < 4; ++cc) {
        int col = cbg * 64 + cc * 16 + (l & 15);
        float bvv = bv[col];
        float buv = b_upd[col];
        #pragma unroll
        for (int r = 0; r < 4; ++r) {
            int row = n0 + rb * 16 + r0 + r;
            out[(size_t)row * D + col] = acc[cc][r] + deg[row] * bvv + buv;
        }
    }
}

extern "C" void kernel_launch(void* const* d_in, const int* in_sizes, int n_in,
                              void* d_out, int out_size, void* d_ws, size_t ws_size,
                              hipStream_t stream)
{
    const float* h     = (const float*)d_in[0];
    const int*   eidx  = (const int*)d_in[1];
    const float* eattr = (const float*)d_in[2];
    const float* W_msg = (const float*)d_in[3];
    const float* b_msg = (const float*)d_in[4];
    const float* W_upd = (const float*)d_in[5];
    const float* b_upd = (const float*)d_in[6];
    float* out = (float*)d_out;

    float* S     = (float*)d_ws;
    float* Ea    = S + (size_t)N_NODES * D;
    float* deg   = Ea + (size_t)N_NODES * D;
    float* wslot = deg + N_NODES;            // 512*128 floats reserved
    ushort* Wfrag = (ushort*)wslot;          // uses first half of wslot
    float* bv    = wslot + 512 * 128;
    int* cnt     = (int*)(bv + 128);
    int* ovf_cnt = cnt + N_NODES;
    int* ovf     = ovf_cnt + 1;
    int* elist   = ovf + OVF_CAP;

    hipMemsetAsync(cnt, 0, (N_NODES + 1) * sizeof(int), stream);
    k_build_w<<<(512 * 128 + 128 + 255) / 256, 256, 0, stream>>>(W_msg, b_msg, W_upd, Wfrag, bv);
    k_bucket<<<(N_EDGES + 255) / 256, 256, 0, stream>>>(eidx, cnt, ovf_cnt, ovf, elist);
    k_gather<<<(N_NODES * 64 + 255) / 256, 256, 0, stream>>>(h, eidx, eattr, cnt, elist, S, Ea, deg);
    k_ovf<<<1, 256, 0, stream>>>(h, eidx, eattr, ovf_cnt, ovf, S, Ea);
    k_node_gemm<<<N_NODES / 32, 256, 0, stream>>>(h, S, Ea, deg, Wfrag, bv, b_upd, out);
}

// Round 4
// 201.063 us; speedup vs baseline: 11.8941x; 1.2881x over previous
//
#include <hip/hip_runtime.h>

#define N_NODES 100000
#define N_EDGES 600000
#define D 128
#define MAXDEG 64
#define OVF_CAP 4096

typedef __attribute__((ext_vector_type(8))) short bf16x8;
typedef __attribute__((ext_vector_type(4))) float f32x4;

static __device__ inline ushort f2bf(float f) {
    unsigned x = __float_as_uint(f);
    unsigned r = (x + 0x7fffu + ((x >> 16) & 1u)) >> 16;  // RNE
    return (ushort)r;
}

// ws layout (bytes from d_ws):
//   Wfrag  : ushort[512*128]  (131072 B)  bf16 fused weight, MFMA B-frag order
//   Wcat32 : float[512*128]   (262144 B)  plain fp32 fused weight (overflow path)
//   bv     : float[128]
//   cnt    : int[N_NODES+1]   (cnt[N_NODES] == ovf_cnt), padded to 100002
//   ovf    : int[OVF_CAP]
//   elist2 : int2[N_NODES*MAXDEG]  (edge id, send idx)
//
// out[n] = [h[n] | S[n] | deg[n]*h[n] | Ea[n]] @ Wcat + deg[n]*bv + b_upd
// Wfrag[(kb*8+cb)*512 + l*8 + i] = Wcat[kb*32+(l>>4)*8+i][cb*16+(l&15)]
// Wcat rows: 0..127 = Wu1; 128..255 = W1@Wu2; 256..383 = W2@Wu2; 384..511 = W3@Wu2
// bv = b_msg @ Wu2

__global__ void k_zero(int* __restrict__ cnt) {
    int i = blockIdx.x * 256 + threadIdx.x;
    if (i < N_NODES + 1) cnt[i] = 0;
}

__global__ void k_build_w(const float* __restrict__ W_msg,
                          const float* __restrict__ b_msg,
                          const float* __restrict__ W_upd,
                          ushort* __restrict__ Wfrag,
                          float* __restrict__ Wcat32,
                          float* __restrict__ bv)
{
    int gid = blockIdx.x * 256 + threadIdx.x;
    if (gid < 512 * 128) {
        int i = gid & 7;
        int l = (gid >> 3) & 63;
        int fb = gid >> 9;          // kb*8 + cb
        int kb = fb >> 3, cb = fb & 7;
        int k = kb * 32 + ((l >> 4) * 8) + i;
        int j = cb * 16 + (l & 15);
        float acc;
        if (k < 128) {
            acc = W_upd[k * 128 + j];
        } else {
            int r = k - 128;
            acc = 0.f;
            #pragma unroll 4
            for (int dd = 0; dd < 128; ++dd)
                acc += W_msg[r * 128 + dd] * W_upd[(128 + dd) * 128 + j];
        }
        Wfrag[gid] = f2bf(acc);
        Wcat32[k * 128 + j] = acc;
    } else if (gid < 512 * 128 + 128) {
        int j = gid - 512 * 128;
        float acc = 0.f;
        for (int dd = 0; dd < 128; ++dd)
            acc += b_msg[dd] * W_upd[(128 + dd) * 128 + j];
        bv[j] = acc;
    }
}

// Bucket edges by receiver; store (edge id, send idx) pairs.
__global__ void k_bucket(const int* __restrict__ eidx,
                         int* __restrict__ cnt,
                         int* __restrict__ ovf,
                         int2* __restrict__ elist2)
{
    int e = blockIdx.x * 256 + threadIdx.x;
    if (e >= N_EDGES) return;
    int s = eidx[e];
    int r = eidx[N_EDGES + e];
    int slot = atomicAdd(cnt + r, 1);
    if (slot < MAXDEG) {
        elist2[(size_t)r * MAXDEG + slot] = make_int2(e, s);
    } else {
        int p = atomicAdd(cnt + N_NODES, 1);
        if (p < OVF_CAP) ovf[p] = e;
    }
}

// Fused gather + GEMM. 256 thr = 4 waves per block, 32 nodes per block.
// Phase 1: wave w gathers nodes w*8..w*8+7 (edge sums in regs, bf16 into LDS).
// Phase 2: MFMA [32,512]@[512,128] tile; wave w does rows 16*(w>>1), cols 64*(w&1).
__global__ __launch_bounds__(256, 4) void k_fused(
    const float* __restrict__ h,
    const float* __restrict__ ea,
    const int* __restrict__ cnt,
    const int2* __restrict__ elist2,
    const ushort* __restrict__ Wfrag,
    const float* __restrict__ bv,
    const float* __restrict__ b_upd,
    float* __restrict__ out)
{
    __shared__ ushort Xs[32][520];   // bf16 X tile, padded row
    __shared__ float degL[32];
    const int tid = threadIdx.x;
    const int lane = tid & 63;
    const int wv = tid >> 6;
    const int n0 = blockIdx.x * 32;

    for (int u = 0; u < 8; ++u) {
        const int i = wv * 8 + u;
        const int n = n0 + i;
        const int c = cnt[n];
        const int m = c < MAXDEG ? c : MAXDEG;
        const float2 hn = *(const float2*)(h + (size_t)n * D + lane * 2);
        int2 es = make_int2(0, 0);
        if (lane < m) es = elist2[(size_t)n * MAXDEG + lane];

        float Sx = 0.f, Sy = 0.f, Ex = 0.f, Ey = 0.f;
        int t = 0;
        for (; t + 4 <= m; t += 4) {
            int e0 = __shfl(es.x, t + 0), s0 = __shfl(es.y, t + 0);
            int e1 = __shfl(es.x, t + 1), s1 = __shfl(es.y, t + 1);
            int e2 = __shfl(es.x, t + 2), s2 = __shfl(es.y, t + 2);
            int e3 = __shfl(es.x, t + 3), s3 = __shfl(es.y, t + 3);
            float2 a0 = *(const float2*)(h  + (size_t)s0 * D + lane * 2);
            float2 a1 = *(const float2*)(h  + (size_t)s1 * D + lane * 2);
            float2 a2 = *(const float2*)(h  + (size_t)s2 * D + lane * 2);
            float2 a3 = *(const float2*)(h  + (size_t)s3 * D + lane * 2);
            float2 b0 = *(const float2*)(ea + (size_t)e0 * D + lane * 2);
            float2 b1 = *(const float2*)(ea + (size_t)e1 * D + lane * 2);
            float2 b2 = *(const float2*)(ea + (size_t)e2 * D + lane * 2);
            float2 b3 = *(const float2*)(ea + (size_t)e3 * D + lane * 2);
            Sx += (a0.x + a1.x) + (a2.x + a3.x);
            Sy += (a0.y + a1.y) + (a2.y + a3.y);
            Ex += (b0.x + b1.x) + (b2.x + b3.x);
            Ey += (b0.y + b1.y) + (b2.y + b3.y);
        }
        for (; t < m; ++t) {
            int e = __shfl(es.x, t), s = __shfl(es.y, t);
            float2 a = *(const float2*)(h  + (size_t)s * D + lane * 2);
            float2 b = *(const float2*)(ea + (size_t)e * D + lane * 2);
            Sx += a.x; Sy += a.y; Ex += b.x; Ey += b.y;
        }
        const float dv = (float)c;
        ushort2 q;
        q.x = f2bf(hn.x);      q.y = f2bf(hn.y);
        *(ushort2*)&Xs[i][      lane * 2] = q;
        q.x = f2bf(Sx);        q.y = f2bf(Sy);
        *(ushort2*)&Xs[i][128 + lane * 2] = q;
        q.x = f2bf(dv * hn.x); q.y = f2bf(dv * hn.y);
        *(ushort2*)&Xs[i][256 + lane * 2] = q;
        q.x = f2bf(Ex);        q.y = f2bf(Ey);
        *(ushort2*)&Xs[i][384 + lane * 2] = q;
        if (lane == 0) degL[i] = dv;
    }
    __syncthreads();

    const int rb = wv >> 1;         // row block (16 rows)
    const int cbg = wv & 1;         // col group (64 cols)
    const int arow = rb * 16 + (lane & 15);
    const int koff = (lane >> 4) * 8;

    f32x4 acc[4] = {};
    for (int kb = 0; kb < 16; ++kb) {
        bf16x8 a = *(const bf16x8*)&Xs[arow][kb * 32 + koff];
        #pragma unroll
        for (int cc = 0; cc < 4; ++cc) {
            int fb = kb * 8 + cbg * 4 + cc;
            bf16x8 b = *(const bf16x8*)(Wfrag + ((size_t)fb * 64 + lane) * 8);
            acc[cc] = __builtin_amdgcn_mfma_f32_16x16x32_bf16(a, b, acc[cc], 0, 0, 0);
        }
    }

    const int r0 = (lane >> 4) * 4;
    #pragma unroll
    for (int cc = 0; cc < 4; ++cc) {
        int col = cbg * 64 + cc * 16 + (lane & 15);
        float bvv = bv[col];
        float buv = b_upd[col];
        #pragma unroll
        for (int r = 0; r < 4; ++r) {
            int rl = rb * 16 + r0 + r;
            out[(size_t)(n0 + rl) * D + col] = acc[cc][r] + degL[rl] * bvv + buv;
        }
    }
}

// Overflow edges (expected 0): add h_s@(W1@Wu2) + ea@(W3@Wu2) into out[rec].
__global__ void k_ovf(const float* __restrict__ h,
                      const int* __restrict__ eidx,
                      const float* __restrict__ ea,
                      const int* __restrict__ cnt,
                      const int* __restrict__ ovf,
                      const float* __restrict__ Wcat32,
                      float* __restrict__ out)
{
    int ncnt = cnt[N_NODES];
    if (ncnt > OVF_CAP) ncnt = OVF_CAP;
    if (ncnt <= 0) return;
    int lane = threadIdx.x & 63;
    int w = threadIdx.x >> 6;
    for (int i = w; i < ncnt; i += 4) {
        int e = ovf[i];
        int s = eidx[e];
        int r = eidx[N_EDGES + e];
        float acc0 = 0.f, acc1 = 0.f;
        for (int dd = 0; dd < 128; ++dd) {
            float hs = h[(size_t)s * D + dd];
            float ev = ea[(size_t)e * D + dd];
            acc0 += hs * Wcat32[(128 + dd) * 128 + lane * 2]     + ev * Wcat32[(384 + dd) * 128 + lane * 2];
            acc1 += hs * Wcat32[(128 + dd) * 128 + lane * 2 + 1] + ev * Wcat32[(384 + dd) * 128 + lane * 2 + 1];
        }
        atomicAdd(out + (size_t)r * D + lane * 2 + 0, acc0);
        atomicAdd(out + (size_t)r * D + lane * 2 + 1, acc1);
    }
}

extern "C" void kernel_launch(void* const* d_in, const int* in_sizes, int n_in,
                              void* d_out, int out_size, void* d_ws, size_t ws_size,
                              hipStream_t stream)
{
    const float* h     = (const float*)d_in[0];
    const int*   eidx  = (const int*)d_in[1];
    const float* eattr = (const float*)d_in[2];
    const float* W_msg = (const float*)d_in[3];
    const float* b_msg = (const float*)d_in[4];
    const float* W_upd = (const float*)d_in[5];
    const float* b_upd = (const float*)d_in[6];
    float* out = (float*)d_out;

    ushort* Wfrag  = (ushort*)d_ws;
    float*  Wcat32 = (float*)((char*)d_ws + 131072);
    float*  bv     = Wcat32 + 512 * 128;
    int*    cnt    = (int*)(bv + 128);        // N_NODES+1 used, +pad
    int*    ovf    = cnt + 100002;
    int2*   elist2 = (int2*)(ovf + OVF_CAP);

    k_zero<<<(N_NODES + 1 + 255) / 256, 256, 0, stream>>>(cnt);
    k_build_w<<<(512 * 128 + 128 + 255) / 256, 256, 0, stream>>>(W_msg, b_msg, W_upd, Wfrag, Wcat32, bv);
    k_bucket<<<(N_EDGES + 255) / 256, 256, 0, stream>>>(eidx, cnt, ovf, elist2);
    k_fused<<<N_NODES / 32, 256, 0, stream>>>(h, eattr, cnt, elist2, Wfrag, bv, b_upd, out);
    k_ovf<<<1, 256, 0, stream>>>(h, eidx, eattr, cnt, ovf, Wcat32, out);
}

// Round 5
// 175.869 us; speedup vs baseline: 13.5979x; 1.1433x over previous
//
#include <hip/hip_runtime.h>

#define N_NODES 100000
#define N_EDGES 600000
#define D 128
#define MAXDEG 64
#define OVF_CAP 4096
#define BM 16              // nodes per block

typedef __attribute__((ext_vector_type(8))) short bf16x8;
typedef __attribute__((ext_vector_type(4))) float f32x4;
typedef __attribute__((ext_vector_type(2))) float f32x2;

static __device__ inline ushort f2bf(float f) {
    unsigned x = __float_as_uint(f);
    unsigned r = (x + 0x7fffu + ((x >> 16) & 1u)) >> 16;  // RNE
    return (ushort)r;
}

static __device__ inline f32x2 nt_load2(const float* p) {
    return __builtin_nontemporal_load((const f32x2*)p);
}

// ws layout (bytes from d_ws):
//   Wfrag  : ushort[512*128]  bf16 fused weight, MFMA B-frag order
//   Wcat32 : float[512*128]   fp32 fused weight (overflow path)
//   bv     : float[128]
//   cnt    : int[N_NODES+1]   (cnt[N_NODES] == ovf_cnt), padded to 100002
//   ovf    : int[OVF_CAP]
//   elist2 : int2[N_NODES*MAXDEG]  (edge id, send idx)
//
// out[n] = [h[n] | S[n] | deg[n]*h[n] | Ea[n]] @ Wcat + deg[n]*bv + b_upd
// Wfrag[(kb*8+cb)*512 + l*8 + i] = Wcat[kb*32+(l>>4)*8+i][cb*16+(l&15)]
// Wcat rows: 0..127 = Wu1; 128..255 = W1@Wu2; 256..383 = W2@Wu2; 384..511 = W3@Wu2
// bv = b_msg @ Wu2

__global__ void k_zero(int* __restrict__ cnt) {
    int i = blockIdx.x * 256 + threadIdx.x;
    if (i < N_NODES + 1) cnt[i] = 0;
}

__global__ void k_build_w(const float* __restrict__ W_msg,
                          const float* __restrict__ b_msg,
                          const float* __restrict__ W_upd,
                          ushort* __restrict__ Wfrag,
                          float* __restrict__ Wcat32,
                          float* __restrict__ bv)
{
    int gid = blockIdx.x * 256 + threadIdx.x;
    if (gid < 512 * 128) {
        int i = gid & 7;
        int l = (gid >> 3) & 63;
        int fb = gid >> 9;          // kb*8 + cb
        int kb = fb >> 3, cb = fb & 7;
        int k = kb * 32 + ((l >> 4) * 8) + i;
        int j = cb * 16 + (l & 15);
        float acc;
        if (k < 128) {
            acc = W_upd[k * 128 + j];
        } else {
            int r = k - 128;
            acc = 0.f;
            #pragma unroll 4
            for (int dd = 0; dd < 128; ++dd)
                acc += W_msg[r * 128 + dd] * W_upd[(128 + dd) * 128 + j];
        }
        Wfrag[gid] = f2bf(acc);
        Wcat32[k * 128 + j] = acc;
    } else if (gid < 512 * 128 + 128) {
        int j = gid - 512 * 128;
        float acc = 0.f;
        for (int dd = 0; dd < 128; ++dd)
            acc += b_msg[dd] * W_upd[(128 + dd) * 128 + j];
        bv[j] = acc;
    }
}

// Bucket edges by receiver; store (edge id, send idx) pairs.
__global__ void k_bucket(const int* __restrict__ eidx,
                         int* __restrict__ cnt,
                         int* __restrict__ ovf,
                         int2* __restrict__ elist2)
{
    int e = blockIdx.x * 256 + threadIdx.x;
    if (e >= N_EDGES) return;
    int s = eidx[e];
    int r = eidx[N_EDGES + e];
    int slot = atomicAdd(cnt + r, 1);
    if (slot < MAXDEG) {
        elist2[(size_t)r * MAXDEG + slot] = make_int2(e, s);
    } else {
        int p = atomicAdd(cnt + N_NODES, 1);
        if (p < OVF_CAP) ovf[p] = e;
    }
}

// Fused gather + GEMM. 256 thr = 4 waves, BM=16 nodes per block (4 per wave).
// Phase 1: wave w gathers nodes w*4..w*4+3, software-pipelined.
// Phase 2: MFMA [16,512]@[512,128]; wave w does cols 32*w..+31.
__global__ __launch_bounds__(256, 8) void k_fused(
    const float* __restrict__ h,
    const float* __restrict__ ea,
    const int* __restrict__ cnt,
    const int2* __restrict__ elist2,
    const ushort* __restrict__ Wfrag,
    const float* __restrict__ bv,
    const float* __restrict__ b_upd,
    float* __restrict__ out)
{
    __shared__ ushort Xs[BM][520];   // bf16 X tile, padded row
    __shared__ float degL[BM];
    const int tid = threadIdx.x;
    const int lane = tid & 63;
    const int wv = tid >> 6;
    const int n0 = blockIdx.x * BM;
    const int nb = n0 + wv * 4;

    // software pipeline: preload node 0's metadata
    int2 es = elist2[(size_t)nb * MAXDEG + lane];
    int   c = cnt[nb];
    f32x2 hn = *(const f32x2*)(h + (size_t)nb * D + lane * 2);

    for (int u = 0; u < 4; ++u) {
        const int i = wv * 4 + u;
        const int n = nb + u;
        // prefetch next node's metadata (always in-bounds; unused lanes harmless)
        int2 es_n; int c_n; f32x2 hn_n;
        if (u < 3) {
            es_n = elist2[(size_t)(n + 1) * MAXDEG + lane];
            c_n  = cnt[n + 1];
            hn_n = *(const f32x2*)(h + (size_t)(n + 1) * D + lane * 2);
        }
        const int m = c < MAXDEG ? c : MAXDEG;

        float Sx = 0.f, Sy = 0.f, Ex = 0.f, Ey = 0.f;
        int t = 0;
        for (; t + 4 <= m; t += 4) {
            int e0 = __shfl(es.x, t + 0), s0 = __shfl(es.y, t + 0);
            int e1 = __shfl(es.x, t + 1), s1 = __shfl(es.y, t + 1);
            int e2 = __shfl(es.x, t + 2), s2 = __shfl(es.y, t + 2);
            int e3 = __shfl(es.x, t + 3), s3 = __shfl(es.y, t + 3);
            f32x2 a0 = *(const f32x2*)(h + (size_t)s0 * D + lane * 2);
            f32x2 a1 = *(const f32x2*)(h + (size_t)s1 * D + lane * 2);
            f32x2 a2 = *(const f32x2*)(h + (size_t)s2 * D + lane * 2);
            f32x2 a3 = *(const f32x2*)(h + (size_t)s3 * D + lane * 2);
            f32x2 b0 = nt_load2(ea + (size_t)e0 * D + lane * 2);
            f32x2 b1 = nt_load2(ea + (size_t)e1 * D + lane * 2);
            f32x2 b2 = nt_load2(ea + (size_t)e2 * D + lane * 2);
            f32x2 b3 = nt_load2(ea + (size_t)e3 * D + lane * 2);
            Sx += (a0[0] + a1[0]) + (a2[0] + a3[0]);
            Sy += (a0[1] + a1[1]) + (a2[1] + a3[1]);
            Ex += (b0[0] + b1[0]) + (b2[0] + b3[0]);
            Ey += (b0[1] + b1[1]) + (b2[1] + b3[1]);
        }
        for (; t < m; ++t) {
            int e = __shfl(es.x, t), s = __shfl(es.y, t);
            f32x2 a = *(const f32x2*)(h + (size_t)s * D + lane * 2);
            f32x2 b = nt_load2(ea + (size_t)e * D + lane * 2);
            Sx += a[0]; Sy += a[1]; Ex += b[0]; Ey += b[1];
        }
        const float dv = (float)c;
        ushort2 q;
        q.x = f2bf(hn[0]);      q.y = f2bf(hn[1]);
        *(ushort2*)&Xs[i][      lane * 2] = q;
        q.x = f2bf(Sx);         q.y = f2bf(Sy);
        *(ushort2*)&Xs[i][128 + lane * 2] = q;
        q.x = f2bf(dv * hn[0]); q.y = f2bf(dv * hn[1]);
        *(ushort2*)&Xs[i][256 + lane * 2] = q;
        q.x = f2bf(Ex);         q.y = f2bf(Ey);
        *(ushort2*)&Xs[i][384 + lane * 2] = q;
        if (lane == 0) degL[i] = dv;
        es = es_n; c = c_n; hn = hn_n;
    }
    __syncthreads();

    const int arow = lane & 15;
    const int koff = (lane >> 4) * 8;

    f32x4 acc[2] = {};
    for (int kb = 0; kb < 16; ++kb) {
        bf16x8 a = *(const bf16x8*)&Xs[arow][kb * 32 + koff];
        #pragma unroll
        for (int cc = 0; cc < 2; ++cc) {
            int fb = kb * 8 + wv * 2 + cc;
            bf16x8 b = *(const bf16x8*)(Wfrag + ((size_t)fb * 64 + lane) * 8);
            acc[cc] = __builtin_amdgcn_mfma_f32_16x16x32_bf16(a, b, acc[cc], 0, 0, 0);
        }
    }

    const int r0 = (lane >> 4) * 4;
    #pragma unroll
    for (int cc = 0; cc < 2; ++cc) {
        int col = wv * 32 + cc * 16 + (lane & 15);
        float bvv = bv[col];
        float buv = b_upd[col];
        #pragma unroll
        for (int r = 0; r < 4; ++r) {
            int rl = r0 + r;
            out[(size_t)(n0 + rl) * D + col] = acc[cc][r] + degL[rl] * bvv + buv;
        }
    }
}

// Overflow edges (expected 0): add h_s@(W1@Wu2) + ea@(W3@Wu2) into out[rec].
__global__ void k_ovf(const float* __restrict__ h,
                      const int* __restrict__ eidx,
                      const float* __restrict__ ea,
                      const int* __restrict__ cnt,
                      const int* __restrict__ ovf,
                      const float* __restrict__ Wcat32,
                      float* __restrict__ out)
{
    int ncnt = cnt[N_NODES];
    if (ncnt > OVF_CAP) ncnt = OVF_CAP;
    if (ncnt <= 0) return;
    int lane = threadIdx.x & 63;
    int w = threadIdx.x >> 6;
    for (int i = w; i < ncnt; i += 4) {
        int e = ovf[i];
        int s = eidx[e];
        int r = eidx[N_EDGES + e];
        float acc0 = 0.f, acc1 = 0.f;
        for (int dd = 0; dd < 128; ++dd) {
            float hs = h[(size_t)s * D + dd];
            float ev = ea[(size_t)e * D + dd];
            acc0 += hs * Wcat32[(128 + dd) * 128 + lane * 2]     + ev * Wcat32[(384 + dd) * 128 + lane * 2];
            acc1 += hs * Wcat32[(128 + dd) * 128 + lane * 2 + 1] + ev * Wcat32[(384 + dd) * 128 + lane * 2 + 1];
        }
        atomicAdd(out + (size_t)r * D + lane * 2 + 0, acc0);
        atomicAdd(out + (size_t)r * D + lane * 2 + 1, acc1);
    }
}

extern "C" void kernel_launch(void* const* d_in, const int* in_sizes, int n_in,
                              void* d_out, int out_size, void* d_ws, size_t ws_size,
                              hipStream_t stream)
{
    const float* h     = (const float*)d_in[0];
    const int*   eidx  = (const int*)d_in[1];
    const float* eattr = (const float*)d_in[2];
    const float* W_msg = (const float*)d_in[3];
    const float* b_msg = (const float*)d_in[4];
    const float* W_upd = (const float*)d_in[5];
    const float* b_upd = (const float*)d_in[6];
    float* out = (float*)d_out;

    ushort* Wfrag  = (ushort*)d_ws;
    float*  Wcat32 = (float*)((char*)d_ws + 131072);
    float*  bv     = Wcat32 + 512 * 128;
    int*    cnt    = (int*)(bv + 128);        // N_NODES+1 used, +pad
    int*    ovf    = cnt + 100002;
    int2*   elist2 = (int2*)(ovf + OVF_CAP);

    k_zero<<<(N_NODES + 1 + 255) / 256, 256, 0, stream>>>(cnt);
    k_build_w<<<(512 * 128 + 128 + 255) / 256, 256, 0, stream>>>(W_msg, b_msg, W_upd, Wfrag, Wcat32, bv);
    k_bucket<<<(N_EDGES + 255) / 256, 256, 0, stream>>>(eidx, cnt, ovf, elist2);
    k_fused<<<N_NODES / BM, 256, 0, stream>>>(h, eattr, cnt, elist2, Wfrag, bv, b_upd, out);
    k_ovf<<<1, 256, 0, stream>>>(h, eidx, eattr, cnt, ovf, Wcat32, out);
}